// Round 1
// baseline (3863.009 us; speedup 1.0000x reference)
//
#include <hip/hip_runtime.h>

#define B_ 8
#define S_ 4096
#define H_ 768
#define C_ 64
#define NB_ 64
#define M_ (B_*S_)   // 32768 rows

typedef _Float16 f16x8 __attribute__((ext_vector_type(8)));
typedef _Float16 f16x4 __attribute__((ext_vector_type(4)));
typedef float    f32x4 __attribute__((ext_vector_type(4)));

// ---------------------------------------------------------------------------
// Weight transpose + f16 cast: WT[n][k] = (f16) W[k][n]
// ---------------------------------------------------------------------------
__global__ __launch_bounds__(256) void k_transpose(const float* __restrict__ src,
                                                   _Float16* __restrict__ dst) {
  __shared__ float tile[32][33];
  const int t = threadIdx.x;
  const int tx = t & 31, ty = t >> 5;              // ty 0..7
  const int n0 = blockIdx.x * 32, k0 = blockIdx.y * 32;
#pragma unroll
  for (int i = 0; i < 4; ++i)
    tile[ty + i*8][tx] = src[(k0 + ty + i*8) * H_ + n0 + tx];
  __syncthreads();
#pragma unroll
  for (int i = 0; i < 4; ++i)
    dst[(n0 + ty + i*8) * H_ + k0 + tx] = (_Float16)tile[tx][ty + i*8];
}

// ---------------------------------------------------------------------------
// Fused Q/K/V GEMM (f16 MFMA 16x16x32). Tile 64(M) x 128(N), 256 threads.
// A = x (f32->f16 on stage-in), B = W from pre-transposed WT[n][k].
// ---------------------------------------------------------------------------
__global__ __launch_bounds__(256) void k_gemm_qkv(
    const float* __restrict__ x,
    const _Float16* __restrict__ WqT, const _Float16* __restrict__ WkT,
    const _Float16* __restrict__ WvT,
    _Float16* __restrict__ Qb, _Float16* __restrict__ Kb, _Float16* __restrict__ Vb) {
  __shared__ _Float16 xs[64][40];        // [m][k] k-stride 40 (pad: 2-way only)
  __shared__ _Float16 ws[3][128][40];    // [mat][n][k]
  const int t = threadIdx.x;
  const int m0 = blockIdx.x * 64, n0 = blockIdx.y * 128;
  const int lane = t & 63, wv = t >> 6;
  const int lm = lane & 15, qd = lane >> 4;
  const int sm = t >> 2, sk = (t & 3) * 8;   // x staging
  const int wn = t >> 1, wk = (t & 1) * 16;  // W staging

  f32x4 acc[3][4][2];
#pragma unroll
  for (int a = 0; a < 3; ++a)
#pragma unroll
    for (int i = 0; i < 4; ++i)
#pragma unroll
      for (int n = 0; n < 2; ++n)
        acc[a][i][n] = (f32x4){0.f, 0.f, 0.f, 0.f};

  for (int kk = 0; kk < 24; ++kk) {
    const int k0 = kk * 32;
    __syncthreads();
    { // stage x tile 64x32 (f32 -> f16)
      const f32x4* xp = (const f32x4*)&x[(m0 + sm) * H_ + k0 + sk];
      f32x4 f0 = xp[0], f1 = xp[1];
      f16x8 xv;
#pragma unroll
      for (int j = 0; j < 4; ++j) { xv[j] = (_Float16)f0[j]; xv[4 + j] = (_Float16)f1[j]; }
      *(f16x8*)&xs[sm][sk] = xv;
    }
    { // stage 3 W tiles 128x32 (already f16, already [n][k])
      const f16x8* wp = (const f16x8*)&WqT[(n0 + wn) * H_ + k0 + wk];
      *(f16x8*)&ws[0][wn][wk] = wp[0]; *(f16x8*)&ws[0][wn][wk + 8] = wp[1];
      wp = (const f16x8*)&WkT[(n0 + wn) * H_ + k0 + wk];
      *(f16x8*)&ws[1][wn][wk] = wp[0]; *(f16x8*)&ws[1][wn][wk + 8] = wp[1];
      wp = (const f16x8*)&WvT[(n0 + wn) * H_ + k0 + wk];
      *(f16x8*)&ws[2][wn][wk] = wp[0]; *(f16x8*)&ws[2][wn][wk + 8] = wp[1];
    }
    __syncthreads();
    f16x8 af[4];
#pragma unroll
    for (int i = 0; i < 4; ++i) af[i] = *(f16x8*)&xs[i*16 + lm][qd*8];
#pragma unroll
    for (int a = 0; a < 3; ++a)
#pragma unroll
      for (int n = 0; n < 2; ++n) {
        f16x8 bfr = *(f16x8*)&ws[a][wv*32 + n*16 + lm][qd*8];
#pragma unroll
        for (int i = 0; i < 4; ++i)
          acc[a][i][n] = __builtin_amdgcn_mfma_f32_16x16x32_f16(af[i], bfr, acc[a][i][n], 0, 0, 0);
      }
  }
  // epilogue: D[row=(lane>>4)*4+r][col=lane&15]
#pragma unroll
  for (int i = 0; i < 4; ++i)
#pragma unroll
    for (int n = 0; n < 2; ++n) {
      const int ng = n0 + wv*32 + n*16 + lm;
#pragma unroll
      for (int r = 0; r < 4; ++r) {
        const int mg = m0 + i*16 + qd*4 + r;
        Qb[mg * H_ + ng] = (_Float16)acc[0][i][n][r];
        Kb[mg * H_ + ng] = (_Float16)acc[1][i][n][r];
        Vb[mg * H_ + ng] = (_Float16)acc[2][i][n][r];
      }
    }
}

// ---------------------------------------------------------------------------
// t = x @ W1   [32768 x 16]
// ---------------------------------------------------------------------------
__global__ __launch_bounds__(256) void k_tgemm(const float* __restrict__ x,
                                               const float* __restrict__ W1,
                                               float* __restrict__ tbuf) {
  __shared__ float w1s[768 * 16];
  __shared__ float xs[64 * 129];
  const int t = threadIdx.x;
  const int m0 = blockIdx.x * 64;
  for (int i = t; i < 768 * 16 / 4; i += 256)
    ((f32x4*)w1s)[i] = ((const f32x4*)W1)[i];
  const int row = t & 63, cg = t >> 6;
  f32x4 acc = (f32x4){0.f, 0.f, 0.f, 0.f};
  for (int kc = 0; kc < 768; kc += 128) {
    __syncthreads();
    for (int i = 0; i < 32; ++i) {
      const int idx = t + 256 * i;              // 0..8191
      const int r = idx >> 7, c = idx & 127;
      xs[r * 129 + c] = x[(m0 + r) * H_ + kc + c];
    }
    __syncthreads();
#pragma unroll 8
    for (int kl = 0; kl < 128; ++kl) {
      const float a = xs[row * 129 + kl];
      const f32x4 w = *(const f32x4*)&w1s[(kc + kl) * 16 + cg * 4];
#pragma unroll
      for (int j = 0; j < 4; ++j) acc[j] += a * w[j];
    }
  }
  *(f32x4*)&tbuf[(m0 + row) * 16 + cg * 4] = acc;
}

// ---------------------------------------------------------------------------
// a[b,h] = mean_s sigmoid((t@W2)[b,s,h] + bias[h]) ^ (1/16)
// grid (24 h-chunks of 32, 8 b); 256 thr = 32 h x 8 s-groups
// ---------------------------------------------------------------------------
__global__ __launch_bounds__(256) void k_areduce(const float* __restrict__ tbuf,
                                                 const float* __restrict__ W2,
                                                 const float* __restrict__ bias,
                                                 float* __restrict__ abuf) {
  __shared__ float ts[128 * 17];
  __shared__ float rbuf[8 * 32];
  const int t = threadIdx.x;
  const int b = blockIdx.y, hc = blockIdx.x;
  const int hl = t & 31, sg = t >> 5;
  const int h = hc * 32 + hl;
  float w2r[16];
#pragma unroll
  for (int j = 0; j < 16; ++j) w2r[j] = W2[j * H_ + h];
  const float bb = bias[h];
  float asum = 0.f;
  const float* tb = &tbuf[(b * S_) * 16];
  for (int sc = 0; sc < S_; sc += 128) {
    __syncthreads();
    for (int i = 0; i < 8; ++i) {
      const int idx = t + 256 * i;              // 0..2047
      const int sl = idx >> 4, j = idx & 15;
      ts[sl * 17 + j] = tb[(sc + sl) * 16 + j];
    }
    __syncthreads();
    for (int i = 0; i < 16; ++i) {
      const int sl = sg + i * 8;
      float z = bb;
      const float* tr = &ts[sl * 17];
#pragma unroll
      for (int j = 0; j < 16; ++j) z += tr[j] * w2r[j];
      const float sgm = 1.f / (1.f + __expf(-z));
      asum += sqrtf(sqrtf(sqrtf(sqrtf(sgm))));  // ^(1/16)
    }
  }
  rbuf[sg * 32 + hl] = asum;
  __syncthreads();
  if (t < 32) {
    float s = 0.f;
#pragma unroll
    for (int g = 0; g < 8; ++g) s += rbuf[g * 32 + t];
    abuf[b * H_ + hc * 32 + t] = s * (1.f / (float)S_);
  }
}

// ---------------------------------------------------------------------------
// Per block: scores = (qb.kb^T)*tril*scale, w = softmax(scores) (masked zeros
// INCLUDED, as in reference), then write Y = w @ vb into O. Scan adds Q.St.
// grid (64 nb, 8 b), 256 threads.
// ---------------------------------------------------------------------------
__global__ __launch_bounds__(256) void k_scores_y(
    const _Float16* __restrict__ Qb, const _Float16* __restrict__ Kb,
    const _Float16* __restrict__ Vb, float* __restrict__ O) {
  __shared__ float qs[64 * 68];   // [h_local][c]
  __shared__ float ks[64 * 68];   // [h_local][d]
  __shared__ float wb[64 * 68];   // transposed: wb[d][c] = w[c][d]
  __shared__ float vsb[64 * 68];  // [j][e_local]
  const int t = threadIdx.x;
  const int nb = blockIdx.x, b = blockIdx.y;
  const int base = (b * S_ + nb * 64) * H_;
  const int tc = t >> 4, td = t & 15;
  const int srow = t >> 2, sseg = (t & 3) * 16;

  float scr[4][4];
#pragma unroll
  for (int i = 0; i < 4; ++i)
#pragma unroll
    for (int u = 0; u < 4; ++u) scr[i][u] = 0.f;

  for (int hc = 0; hc < 12; ++hc) {
    __syncthreads();
    { // stage q,k chunk transposed -> [h][row]
      const f16x8* qp = (const f16x8*)&Qb[base + srow * H_ + hc * 64 + sseg];
      f16x8 q0 = qp[0], q1 = qp[1];
      const f16x8* kp = (const f16x8*)&Kb[base + srow * H_ + hc * 64 + sseg];
      f16x8 k0 = kp[0], k1 = kp[1];
#pragma unroll
      for (int j = 0; j < 8; ++j) {
        qs[(sseg + j) * 68 + srow] = (float)q0[j];
        qs[(sseg + 8 + j) * 68 + srow] = (float)q1[j];
        ks[(sseg + j) * 68 + srow] = (float)k0[j];
        ks[(sseg + 8 + j) * 68 + srow] = (float)k1[j];
      }
    }
    __syncthreads();
#pragma unroll 4
    for (int h = 0; h < 64; ++h) {
      const f32x4 qv = *(f32x4*)&qs[h * 68 + tc * 4];
      const f32x4 kv = *(f32x4*)&ks[h * 68 + td * 4];
#pragma unroll
      for (int i = 0; i < 4; ++i)
#pragma unroll
        for (int u = 0; u < 4; ++u) scr[i][u] += qv[i] * kv[u];
    }
  }
  const float scale = 0.036084391824351615f;  // 1/sqrt(768)
#pragma unroll
  for (int i = 0; i < 4; ++i)
#pragma unroll
    for (int u = 0; u < 4; ++u) {
      const int c = tc * 4 + i, d = td * 4 + u;
      wb[d * 68 + c] = (d <= c) ? scr[i][u] * scale : 0.f;  // mask by multiplication
    }
  __syncthreads();
  { // softmax over full 64-wide rows (zeros included), 4 threads per row
    const int r = t >> 2, g = t & 3;
    float vals[16];
    float mx = -1e30f;
#pragma unroll
    for (int i = 0; i < 16; ++i) {
      vals[i] = wb[(g * 16 + i) * 68 + r];
      mx = fmaxf(mx, vals[i]);
    }
    mx = fmaxf(mx, __shfl_xor(mx, 1));
    mx = fmaxf(mx, __shfl_xor(mx, 2));
    float sm = 0.f;
#pragma unroll
    for (int i = 0; i < 16; ++i) { vals[i] = __expf(vals[i] - mx); sm += vals[i]; }
    sm += __shfl_xor(sm, 1);
    sm += __shfl_xor(sm, 2);
    const float inv = 1.f / sm;
#pragma unroll
    for (int i = 0; i < 16; ++i) wb[(g * 16 + i) * 68 + r] = vals[i] * inv;
  }
  // Y = w @ vb  -> O (full overwrite; scan accumulates on top)
  for (int ec = 0; ec < 12; ++ec) {
    __syncthreads();
    {
      const f16x8* vp = (const f16x8*)&Vb[base + srow * H_ + ec * 64 + sseg];
      f16x8 v0 = vp[0], v1 = vp[1];
      f32x4 f;
#pragma unroll
      for (int j = 0; j < 4; ++j) f[j] = (float)v0[j];
      *(f32x4*)&vsb[srow * 68 + sseg] = f;
#pragma unroll
      for (int j = 0; j < 4; ++j) f[j] = (float)v0[4 + j];
      *(f32x4*)&vsb[srow * 68 + sseg + 4] = f;
#pragma unroll
      for (int j = 0; j < 4; ++j) f[j] = (float)v1[j];
      *(f32x4*)&vsb[srow * 68 + sseg + 8] = f;
#pragma unroll
      for (int j = 0; j < 4; ++j) f[j] = (float)v1[4 + j];
      *(f32x4*)&vsb[srow * 68 + sseg + 12] = f;
    }
    __syncthreads();
    float y[4][4];
#pragma unroll
    for (int i = 0; i < 4; ++i)
#pragma unroll
      for (int u = 0; u < 4; ++u) y[i][u] = 0.f;
#pragma unroll 4
    for (int j = 0; j < 64; ++j) {
      const f32x4 wv = *(f32x4*)&wb[j * 68 + tc * 4];
      const f32x4 vv = *(f32x4*)&vsb[j * 68 + td * 4];
#pragma unroll
      for (int i = 0; i < 4; ++i)
#pragma unroll
        for (int u = 0; u < 4; ++u) y[i][u] += wv[i] * vv[u];
    }
#pragma unroll
    for (int i = 0; i < 4; ++i) {
      f32x4 yv = {y[i][0], y[i][1], y[i][2], y[i][3]};
      *(f32x4*)&O[base + (tc * 4 + i) * H_ + ec * 64 + td * 4] = yv;
    }
  }
}

// ---------------------------------------------------------------------------
// Sequential scan over 64 blocks.
//   St[h][d] = St[h][d]*a[d] + sum_c K[c][h]*V[c][d]   (update FIRST)
//   O[c][d] += sum_h Q[c][h]*St[h][d]
// grid (24 d-tiles of 32, 8 b), 256 threads, St lives in LDS (fp32).
// ---------------------------------------------------------------------------
__global__ __launch_bounds__(256) void k_scan(
    const _Float16* __restrict__ Qb, const _Float16* __restrict__ Kb,
    const _Float16* __restrict__ Vb, const float* __restrict__ abuf,
    float* __restrict__ O) {
  __shared__ float st[768 * 36];     // St[h][d], d-stride 36
  __shared__ float kqbuf[64 * 132];  // update: kq[c][h] (128-chunk); out: qst[h][c]
  __shared__ float vs[64 * 36];      // V tile [c][d]; reused as pbuf in reduction
  float* pbuf = vs;

  const int t = threadIdx.x;
  const int b = blockIdx.y;
  const int d0 = blockIdx.x * 32;

  const int th = t >> 3, td = t & 7;     // update mapping: 4h x 4d tile
  const int hg = t >> 7, tl = t & 127;   // out: 2 h-groups x 128 threads
  const int otc = tl >> 3, otd = tl & 7; // out tile: 4c x 4d
  const int sc_ = t >> 2, sseg = (t & 3) * 32;  // kq/qst staging
  const int vvc = t >> 3, vd4 = (t & 7) * 4;    // vs staging

  float aR[4];
#pragma unroll
  for (int u = 0; u < 4; ++u) aR[u] = abuf[b * H_ + d0 + td * 4 + u];

  {
    f32x4 z4 = (f32x4){0.f, 0.f, 0.f, 0.f};
    for (int i = t; i < 768 * 36 / 4; i += 256) ((f32x4*)st)[i] = z4;
  }
  __syncthreads();

  for (int blk = 0; blk < NB_; ++blk) {
    const int base = (b * S_ + blk * 64) * H_;
    // stage V tile
#pragma unroll
    for (int rr = 0; rr < 2; ++rr) {
      const int c = vvc + rr * 32;
      f16x4 v4 = *(const f16x4*)&Vb[base + c * H_ + d0 + vd4];
      f32x4 f;
#pragma unroll
      for (int j = 0; j < 4; ++j) f[j] = (float)v4[j];
      *(f32x4*)&vs[c * 36 + vd4] = f;
    }
    // -------- state update --------
    float (*kq)[132] = (float(*)[132])kqbuf;
    for (int hcb = 0; hcb < 6; ++hcb) {
      __syncthreads();
      { // stage K chunk [c][128h]
        const f16x8* kp = (const f16x8*)&Kb[base + sc_ * H_ + hcb * 128 + sseg];
#pragma unroll
        for (int q8 = 0; q8 < 4; ++q8) {
          f16x8 k8 = kp[q8];
          f32x4 f0, f1;
#pragma unroll
          for (int j = 0; j < 4; ++j) { f0[j] = (float)k8[j]; f1[j] = (float)k8[4 + j]; }
          *(f32x4*)&kq[sc_][sseg + q8 * 8] = f0;
          *(f32x4*)&kq[sc_][sseg + q8 * 8 + 4] = f1;
        }
      }
      __syncthreads();
      const int hbase = hcb * 128 + th * 4;
      float stR[4][4];
#pragma unroll
      for (int i = 0; i < 4; ++i) {
        const f32x4 s4 = *(f32x4*)&st[(hbase + i) * 36 + td * 4];
#pragma unroll
        for (int u = 0; u < 4; ++u) stR[i][u] = s4[u] * aR[u];  // decay along d
      }
#pragma unroll 2
      for (int c = 0; c < 64; ++c) {
        const f32x4 kv = *(f32x4*)&kq[c][th * 4];
        const f32x4 vv = *(f32x4*)&vs[c * 36 + td * 4];
#pragma unroll
        for (int i = 0; i < 4; ++i)
#pragma unroll
          for (int u = 0; u < 4; ++u) stR[i][u] += kv[i] * vv[u];
      }
#pragma unroll
      for (int i = 0; i < 4; ++i) {
        f32x4 s4 = {stR[i][0], stR[i][1], stR[i][2], stR[i][3]};
        *(f32x4*)&st[(hbase + i) * 36 + td * 4] = s4;
      }
    }
    // -------- output: O += Q . St --------
    float (*qst)[64] = (float(*)[64])kqbuf;
    float oacc[4][4];
#pragma unroll
    for (int i = 0; i < 4; ++i)
#pragma unroll
      for (int u = 0; u < 4; ++u) oacc[i][u] = 0.f;
    for (int hcb = 0; hcb < 6; ++hcb) {
      __syncthreads();
      { // stage Q chunk transposed -> [h][c]
        const f16x8* qp = (const f16x8*)&Qb[base + sc_ * H_ + hcb * 128 + sseg];
#pragma unroll
        for (int q8 = 0; q8 < 4; ++q8) {
          f16x8 q8v = qp[q8];
#pragma unroll
          for (int j = 0; j < 8; ++j) qst[sseg + q8 * 8 + j][sc_] = (float)q8v[j];
        }
      }
      __syncthreads();
#pragma unroll 2
      for (int hh = 0; hh < 64; ++hh) {
        const int hl = hg * 64 + hh;
        const f32x4 qv = *(f32x4*)&qst[hl][otc * 4];
        const f32x4 sv = *(f32x4*)&st[(hcb * 128 + hl) * 36 + otd * 4];
#pragma unroll
        for (int i = 0; i < 4; ++i)
#pragma unroll
          for (int u = 0; u < 4; ++u) oacc[i][u] += qv[i] * sv[u];
      }
    }
    __syncthreads();   // vs dead; reuse as pbuf
    if (hg == 0) {
#pragma unroll
      for (int i = 0; i < 4; ++i) {
        f32x4 p = {oacc[i][0], oacc[i][1], oacc[i][2], oacc[i][3]};
        *(f32x4*)&pbuf[(otc * 4 + i) * 36 + otd * 4] = p;
      }
    }
    __syncthreads();
    if (hg == 1) {
#pragma unroll
      for (int i = 0; i < 4; ++i) {
        const int c = otc * 4 + i;
        const f32x4 p = *(f32x4*)&pbuf[c * 36 + otd * 4];
        f32x4* op = (f32x4*)&O[base + c * H_ + d0 + otd * 4];
        f32x4 o = *op;
#pragma unroll
        for (int u = 0; u < 4; ++u) o[u] += p[u] + oacc[i][u];
        *op = o;
      }
    }
    __syncthreads();
  }
}

// ---------------------------------------------------------------------------
extern "C" void kernel_launch(void* const* d_in, const int* in_sizes, int n_in,
                              void* d_out, int out_size, void* d_ws, size_t ws_size,
                              hipStream_t stream) {
  (void)in_sizes; (void)n_in; (void)out_size; (void)ws_size;
  const float* x    = (const float*)d_in[0];
  const float* Wq   = (const float*)d_in[1];
  const float* Wk   = (const float*)d_in[2];
  const float* Wv   = (const float*)d_in[3];
  const float* W1   = (const float*)d_in[4];
  const float* W2   = (const float*)d_in[5];
  const float* bias = (const float*)d_in[6];
  float* O = (float*)d_out;

  // workspace layout (~156.7 MB): Q,K,V f16; transposed weights f16; t; a
  char* ws = (char*)d_ws;
  _Float16* Qb  = (_Float16*)ws;
  _Float16* Kb  = Qb + (size_t)M_ * H_;
  _Float16* Vb  = Kb + (size_t)M_ * H_;
  _Float16* WqT = Vb + (size_t)M_ * H_;
  _Float16* WkT = WqT + H_ * H_;
  _Float16* WvT = WkT + H_ * H_;
  float* tbuf = (float*)(WvT + H_ * H_);
  float* abuf = tbuf + (size_t)M_ * 16;

  k_transpose<<<dim3(24, 24), 256, 0, stream>>>(Wq, WqT);
  k_transpose<<<dim3(24, 24), 256, 0, stream>>>(Wk, WkT);
  k_transpose<<<dim3(24, 24), 256, 0, stream>>>(Wv, WvT);
  k_gemm_qkv<<<dim3(512, 6), 256, 0, stream>>>(x, WqT, WkT, WvT, Qb, Kb, Vb);
  k_tgemm<<<dim3(512), 256, 0, stream>>>(x, W1, tbuf);
  k_areduce<<<dim3(24, 8), 256, 0, stream>>>(tbuf, W2, bias, abuf);
  k_scores_y<<<dim3(64, 8), 256, 0, stream>>>(Qb, Kb, Vb, O);
  k_scan<<<dim3(24, 8), 256, 0, stream>>>(Qb, Kb, Vb, abuf, O);
}

// Round 2
// 1535.824 us; speedup vs baseline: 2.5153x; 2.5153x over previous
//
#include <hip/hip_runtime.h>

#define B_ 8
#define S_ 4096
#define H_ 768
#define C_ 64
#define NB_ 64
#define M_ (B_*S_)   // 32768 rows

typedef _Float16 f16x8 __attribute__((ext_vector_type(8)));
typedef _Float16 f16x4 __attribute__((ext_vector_type(4)));
typedef float    f32x4 __attribute__((ext_vector_type(4)));

// ---------------------------------------------------------------------------
// Weight transpose + f16 cast: WT[n][k] = (f16) W[k][n]
// ---------------------------------------------------------------------------
__global__ __launch_bounds__(256) void k_transpose(const float* __restrict__ src,
                                                   _Float16* __restrict__ dst) {
  __shared__ float tile[32][33];
  const int t = threadIdx.x;
  const int tx = t & 31, ty = t >> 5;              // ty 0..7
  const int n0 = blockIdx.x * 32, k0 = blockIdx.y * 32;
#pragma unroll
  for (int i = 0; i < 4; ++i)
    tile[ty + i*8][tx] = src[(k0 + ty + i*8) * H_ + n0 + tx];
  __syncthreads();
#pragma unroll
  for (int i = 0; i < 4; ++i)
    dst[(n0 + ty + i*8) * H_ + k0 + tx] = (_Float16)tile[tx][ty + i*8];
}

// ---------------------------------------------------------------------------
// Fused Q/K/V GEMM (f16 MFMA 16x16x32). Tile 64(M) x 128(N), 256 threads.
// Writes: Qb[s][h], Vb[s][h] (row-major) and KT[b][h][s], VT[b][d][s]
// (transposed, packed f16x4 along s) for the MFMA scan.
// ---------------------------------------------------------------------------
__global__ __launch_bounds__(256) void k_gemm_qkv(
    const float* __restrict__ x,
    const _Float16* __restrict__ WqT, const _Float16* __restrict__ WkT,
    const _Float16* __restrict__ WvT,
    _Float16* __restrict__ Qb, _Float16* __restrict__ Vb,
    _Float16* __restrict__ KT, _Float16* __restrict__ VT) {
  __shared__ _Float16 xs[64][40];        // [m][k]
  __shared__ _Float16 ws[3][128][40];    // [mat][n][k]
  const int t = threadIdx.x;
  const int m0 = blockIdx.x * 64, n0 = blockIdx.y * 128;
  const int lane = t & 63, wv = t >> 6;
  const int lm = lane & 15, qd = lane >> 4;
  const int sm = t >> 2, sk = (t & 3) * 8;   // x staging
  const int wn = t >> 1, wk = (t & 1) * 16;  // W staging

  f32x4 acc[3][4][2];
#pragma unroll
  for (int a = 0; a < 3; ++a)
#pragma unroll
    for (int i = 0; i < 4; ++i)
#pragma unroll
      for (int n = 0; n < 2; ++n)
        acc[a][i][n] = (f32x4){0.f, 0.f, 0.f, 0.f};

  for (int kk = 0; kk < 24; ++kk) {
    const int k0 = kk * 32;
    __syncthreads();
    { // stage x tile 64x32 (f32 -> f16)
      const f32x4* xp = (const f32x4*)&x[(size_t)(m0 + sm) * H_ + k0 + sk];
      f32x4 f0 = xp[0], f1 = xp[1];
      f16x8 xv;
#pragma unroll
      for (int j = 0; j < 4; ++j) { xv[j] = (_Float16)f0[j]; xv[4 + j] = (_Float16)f1[j]; }
      *(f16x8*)&xs[sm][sk] = xv;
    }
    { // stage 3 W tiles 128x32
      const f16x8* wp = (const f16x8*)&WqT[(n0 + wn) * H_ + k0 + wk];
      *(f16x8*)&ws[0][wn][wk] = wp[0]; *(f16x8*)&ws[0][wn][wk + 8] = wp[1];
      wp = (const f16x8*)&WkT[(n0 + wn) * H_ + k0 + wk];
      *(f16x8*)&ws[1][wn][wk] = wp[0]; *(f16x8*)&ws[1][wn][wk + 8] = wp[1];
      wp = (const f16x8*)&WvT[(n0 + wn) * H_ + k0 + wk];
      *(f16x8*)&ws[2][wn][wk] = wp[0]; *(f16x8*)&ws[2][wn][wk + 8] = wp[1];
    }
    __syncthreads();
    f16x8 af[4];
#pragma unroll
    for (int i = 0; i < 4; ++i) af[i] = *(f16x8*)&xs[i*16 + lm][qd*8];
#pragma unroll
    for (int a = 0; a < 3; ++a)
#pragma unroll
      for (int n = 0; n < 2; ++n) {
        f16x8 bfr = *(f16x8*)&ws[a][wv*32 + n*16 + lm][qd*8];
#pragma unroll
        for (int i = 0; i < 4; ++i)
          acc[a][i][n] = __builtin_amdgcn_mfma_f32_16x16x32_f16(af[i], bfr, acc[a][i][n], 0, 0, 0);
      }
  }
  // epilogue: C row=(lane>>4)*4+r (global s), col=lane&15 (global h/d)
#pragma unroll
  for (int i = 0; i < 4; ++i)
#pragma unroll
    for (int n = 0; n < 2; ++n) {
      const int ng = n0 + wv*32 + n*16 + lm;
      const int mg0 = m0 + i*16 + qd*4;
      const int bb = mg0 >> 12, ss = mg0 & (S_ - 1);
#pragma unroll
      for (int r = 0; r < 4; ++r) {
        Qb[(size_t)(mg0 + r) * H_ + ng] = (_Float16)acc[0][i][n][r];
        Vb[(size_t)(mg0 + r) * H_ + ng] = (_Float16)acc[2][i][n][r];
      }
      f16x4 kp, vp;
#pragma unroll
      for (int r = 0; r < 4; ++r) {
        kp[r] = (_Float16)acc[1][i][n][r];
        vp[r] = (_Float16)acc[2][i][n][r];
      }
      *(f16x4*)&KT[((size_t)bb * H_ + ng) * S_ + ss] = kp;
      *(f16x4*)&VT[((size_t)bb * H_ + ng) * S_ + ss] = vp;
    }
}

// ---------------------------------------------------------------------------
// t = x @ W1   [32768 x 16]
// ---------------------------------------------------------------------------
__global__ __launch_bounds__(256) void k_tgemm(const float* __restrict__ x,
                                               const float* __restrict__ W1,
                                               float* __restrict__ tbuf) {
  __shared__ float w1s[768 * 16];
  __shared__ float xs[64 * 129];
  const int t = threadIdx.x;
  const int m0 = blockIdx.x * 64;
  for (int i = t; i < 768 * 16 / 4; i += 256)
    ((f32x4*)w1s)[i] = ((const f32x4*)W1)[i];
  const int row = t & 63, cg = t >> 6;
  f32x4 acc = (f32x4){0.f, 0.f, 0.f, 0.f};
  for (int kc = 0; kc < 768; kc += 128) {
    __syncthreads();
    for (int i = 0; i < 32; ++i) {
      const int idx = t + 256 * i;
      const int r = idx >> 7, c = idx & 127;
      xs[r * 129 + c] = x[(size_t)(m0 + r) * H_ + kc + c];
    }
    __syncthreads();
#pragma unroll 8
    for (int kl = 0; kl < 128; ++kl) {
      const float a = xs[row * 129 + kl];
      const f32x4 w = *(const f32x4*)&w1s[(kc + kl) * 16 + cg * 4];
#pragma unroll
      for (int j = 0; j < 4; ++j) acc[j] += a * w[j];
    }
  }
  *(f32x4*)&tbuf[(size_t)(m0 + row) * 16 + cg * 4] = acc;
}

// ---------------------------------------------------------------------------
// a[b,h] = mean_s sigmoid((t@W2)[b,s,h] + bias[h]) ^ (1/16)
// ---------------------------------------------------------------------------
__global__ __launch_bounds__(256) void k_areduce(const float* __restrict__ tbuf,
                                                 const float* __restrict__ W2,
                                                 const float* __restrict__ bias,
                                                 float* __restrict__ abuf) {
  __shared__ float ts[128 * 17];
  __shared__ float rbuf[8 * 32];
  const int t = threadIdx.x;
  const int b = blockIdx.y, hc = blockIdx.x;
  const int hl = t & 31, sg = t >> 5;
  const int h = hc * 32 + hl;
  float w2r[16];
#pragma unroll
  for (int j = 0; j < 16; ++j) w2r[j] = W2[j * H_ + h];
  const float bb = bias[h];
  float asum = 0.f;
  const float* tb = &tbuf[(size_t)(b * S_) * 16];
  for (int sc = 0; sc < S_; sc += 128) {
    __syncthreads();
    for (int i = 0; i < 8; ++i) {
      const int idx = t + 256 * i;
      const int sl = idx >> 4, j = idx & 15;
      ts[sl * 17 + j] = tb[(size_t)(sc + sl) * 16 + j];
    }
    __syncthreads();
    for (int i = 0; i < 16; ++i) {
      const int sl = sg + i * 8;
      float z = bb;
      const float* tr = &ts[sl * 17];
#pragma unroll
      for (int j = 0; j < 16; ++j) z += tr[j] * w2r[j];
      const float sgm = 1.f / (1.f + __expf(-z));
      asum += sqrtf(sqrtf(sqrtf(sqrtf(sgm))));  // ^(1/16)
    }
  }
  rbuf[sg * 32 + hl] = asum;
  __syncthreads();
  if (t < 32) {
    float s = 0.f;
#pragma unroll
    for (int g = 0; g < 8; ++g) s += rbuf[g * 32 + t];
    abuf[b * H_ + hc * 32 + t] = s * (1.f / (float)S_);
  }
}

// ---------------------------------------------------------------------------
// Per block: scores = (qb.kb^T)*tril*scale, softmax (masked zeros included),
// Y = w @ vb written to O (scan accumulates on top). grid (64 nb, 8 b).
// K staged from transposed KT (vector loads); Q staged via scalar scatter.
// ---------------------------------------------------------------------------
__global__ __launch_bounds__(256) void k_scores_y(
    const _Float16* __restrict__ Qb, const _Float16* __restrict__ KT,
    const _Float16* __restrict__ Vb, float* __restrict__ O) {
  __shared__ float qs[64 * 68];   // [h_local][c]
  __shared__ float ks[64 * 68];   // [h_local][d]
  __shared__ float wb[64 * 68];   // transposed: wb[d][c] = w[c][d]
  __shared__ float vsb[64 * 68];  // [j][e_local]
  const int t = threadIdx.x;
  const int nb = blockIdx.x, b = blockIdx.y;
  const size_t base = ((size_t)b * S_ + nb * 64) * H_;
  const int tc = t >> 4, td = t & 15;
  const int srow = t >> 2, sseg = (t & 3) * 16;

  float scr[4][4];
#pragma unroll
  for (int i = 0; i < 4; ++i)
#pragma unroll
    for (int u = 0; u < 4; ++u) scr[i][u] = 0.f;

  for (int hc = 0; hc < 12; ++hc) {
    __syncthreads();
    { // stage q chunk transposed -> [h][c] (scalar scatter)
      const f16x8* qp = (const f16x8*)&Qb[base + (size_t)srow * H_ + hc * 64 + sseg];
      f16x8 q0 = qp[0], q1 = qp[1];
#pragma unroll
      for (int j = 0; j < 8; ++j) {
        qs[(sseg + j) * 68 + srow] = (float)q0[j];
        qs[(sseg + 8 + j) * 68 + srow] = (float)q1[j];
      }
    }
    { // stage k chunk from KT (already [h][s]) -> vector both sides
      const size_t krow = ((size_t)b * H_ + hc * 64 + srow) * S_ + nb * 64 + sseg;
      f16x8 k0 = *(const f16x8*)&KT[krow];
      f16x8 k1 = *(const f16x8*)&KT[krow + 8];
      f32x4 f;
#pragma unroll
      for (int j = 0; j < 4; ++j) f[j] = (float)k0[j];
      *(f32x4*)&ks[srow * 68 + sseg] = f;
#pragma unroll
      for (int j = 0; j < 4; ++j) f[j] = (float)k0[4 + j];
      *(f32x4*)&ks[srow * 68 + sseg + 4] = f;
#pragma unroll
      for (int j = 0; j < 4; ++j) f[j] = (float)k1[j];
      *(f32x4*)&ks[srow * 68 + sseg + 8] = f;
#pragma unroll
      for (int j = 0; j < 4; ++j) f[j] = (float)k1[4 + j];
      *(f32x4*)&ks[srow * 68 + sseg + 12] = f;
    }
    __syncthreads();
#pragma unroll 4
    for (int h = 0; h < 64; ++h) {
      const f32x4 qv = *(f32x4*)&qs[h * 68 + tc * 4];
      const f32x4 kv = *(f32x4*)&ks[h * 68 + td * 4];
#pragma unroll
      for (int i = 0; i < 4; ++i)
#pragma unroll
        for (int u = 0; u < 4; ++u) scr[i][u] += qv[i] * kv[u];
    }
  }
  const float scale = 0.036084391824351615f;  // 1/sqrt(768)
#pragma unroll
  for (int i = 0; i < 4; ++i)
#pragma unroll
    for (int u = 0; u < 4; ++u) {
      const int c = tc * 4 + i, d = td * 4 + u;
      wb[d * 68 + c] = (d <= c) ? scr[i][u] * scale : 0.f;  // mask by multiplication
    }
  __syncthreads();
  { // softmax over 64-wide rows (zeros included), 4 threads per row
    const int r = t >> 2, g = t & 3;
    float vals[16];
    float mx = -1e30f;
#pragma unroll
    for (int i = 0; i < 16; ++i) {
      vals[i] = wb[(g * 16 + i) * 68 + r];
      mx = fmaxf(mx, vals[i]);
    }
    mx = fmaxf(mx, __shfl_xor(mx, 1));
    mx = fmaxf(mx, __shfl_xor(mx, 2));
    float sm = 0.f;
#pragma unroll
    for (int i = 0; i < 16; ++i) { vals[i] = __expf(vals[i] - mx); sm += vals[i]; }
    sm += __shfl_xor(sm, 1);
    sm += __shfl_xor(sm, 2);
    const float inv = 1.f / sm;
#pragma unroll
    for (int i = 0; i < 16; ++i) wb[(g * 16 + i) * 68 + r] = vals[i] * inv;
  }
  // Y = w @ vb  -> O (full overwrite; scan accumulates on top)
  for (int ec = 0; ec < 12; ++ec) {
    __syncthreads();
    {
      const f16x8* vp = (const f16x8*)&Vb[base + (size_t)srow * H_ + ec * 64 + sseg];
      f16x8 v0 = vp[0], v1 = vp[1];
      f32x4 f;
#pragma unroll
      for (int j = 0; j < 4; ++j) f[j] = (float)v0[j];
      *(f32x4*)&vsb[srow * 68 + sseg] = f;
#pragma unroll
      for (int j = 0; j < 4; ++j) f[j] = (float)v0[4 + j];
      *(f32x4*)&vsb[srow * 68 + sseg + 4] = f;
#pragma unroll
      for (int j = 0; j < 4; ++j) f[j] = (float)v1[j];
      *(f32x4*)&vsb[srow * 68 + sseg + 8] = f;
#pragma unroll
      for (int j = 0; j < 4; ++j) f[j] = (float)v1[4 + j];
      *(f32x4*)&vsb[srow * 68 + sseg + 12] = f;
    }
    __syncthreads();
    float y[4][4];
#pragma unroll
    for (int i = 0; i < 4; ++i)
#pragma unroll
      for (int u = 0; u < 4; ++u) y[i][u] = 0.f;
#pragma unroll 4
    for (int j = 0; j < 64; ++j) {
      const f32x4 wv = *(f32x4*)&wb[j * 68 + tc * 4];
      const f32x4 vv = *(f32x4*)&vsb[j * 68 + td * 4];
#pragma unroll
      for (int i = 0; i < 4; ++i)
#pragma unroll
        for (int u = 0; u < 4; ++u) y[i][u] += wv[i] * vv[u];
    }
#pragma unroll
    for (int i = 0; i < 4; ++i) {
      f32x4 yv = {y[i][0], y[i][1], y[i][2], y[i][3]};
      *(f32x4*)&O[base + (size_t)(tc * 4 + i) * H_ + ec * 64 + td * 4] = yv;
    }
  }
}

// ---------------------------------------------------------------------------
// MFMA scan. grid (24 d-tiles, 8 b), 256 threads (4 waves).
// St[768][32] fp32 lives in MFMA accumulators: wave w owns h-tiles w*12..w*12+11.
// Per step: decay (per-lane mul) + St += K^T.V (MFMA, frags from KT/VT global),
// St -> LDS f16 (StL[d][h]), then O += Q.St (MFMA, wave w owns rows w*16..+15).
// ---------------------------------------------------------------------------
#define STP 776  // StL h-stride (halves): 16B aligned, 2-way-free banks
__global__ __launch_bounds__(256, 2) void k_scan(
    const _Float16* __restrict__ Qb, const _Float16* __restrict__ KT,
    const _Float16* __restrict__ VT, const float* __restrict__ abuf,
    float* __restrict__ O) {
  __shared__ _Float16 StL[32 * STP];
  const int t = threadIdx.x;
  const int b = blockIdx.y;
  const int d0 = blockIdx.x * 32;
  const int w = t >> 6, lane = t & 63;
  const int lm = lane & 15, qd = lane >> 4;

  const float av0 = abuf[b * H_ + d0 + lm];
  const float av1 = abuf[b * H_ + d0 + 16 + lm];

  f32x4 acc[12][2];
#pragma unroll
  for (int mt = 0; mt < 12; ++mt) {
    acc[mt][0] = (f32x4){0.f, 0.f, 0.f, 0.f};
    acc[mt][1] = (f32x4){0.f, 0.f, 0.f, 0.f};
  }

  const size_t ktb = (size_t)b * H_ * S_;               // KT/VT batch base
  const size_t vrow0 = ktb + (size_t)(d0 + lm) * S_;    // VT row, nt=0
  const size_t vrow1 = ktb + (size_t)(d0 + 16 + lm) * S_;

  for (int blk = 0; blk < NB_; ++blk) {
    const int s0 = blk * 64;
    // ---- update: St = St*a + K^T V ----
    f16x8 vf00 = *(const f16x8*)&VT[vrow0 + s0 + qd * 8];
    f16x8 vf01 = *(const f16x8*)&VT[vrow0 + s0 + 32 + qd * 8];
    f16x8 vf10 = *(const f16x8*)&VT[vrow1 + s0 + qd * 8];
    f16x8 vf11 = *(const f16x8*)&VT[vrow1 + s0 + 32 + qd * 8];
#pragma unroll
    for (int mt = 0; mt < 12; ++mt) {
      const size_t arow = ktb + (size_t)((w * 12 + mt) * 16 + lm) * S_ + s0 + qd * 8;
      f16x8 a0 = *(const f16x8*)&KT[arow];
      f16x8 a1 = *(const f16x8*)&KT[arow + 32];
      f32x4 c0 = acc[mt][0] * av0;
      f32x4 c1 = acc[mt][1] * av1;
      c0 = __builtin_amdgcn_mfma_f32_16x16x32_f16(a0, vf00, c0, 0, 0, 0);
      c0 = __builtin_amdgcn_mfma_f32_16x16x32_f16(a1, vf01, c0, 0, 0, 0);
      c1 = __builtin_amdgcn_mfma_f32_16x16x32_f16(a0, vf10, c1, 0, 0, 0);
      c1 = __builtin_amdgcn_mfma_f32_16x16x32_f16(a1, vf11, c1, 0, 0, 0);
      acc[mt][0] = c0;
      acc[mt][1] = c1;
    }
    __syncthreads();   // previous step's StL readers done
    // ---- St -> LDS f16, layout StL[d][h] ----
#pragma unroll
    for (int mt = 0; mt < 12; ++mt) {
      const int h = (w * 12 + mt) * 16 + qd * 4;
      f16x4 p0, p1;
#pragma unroll
      for (int r = 0; r < 4; ++r) {
        p0[r] = (_Float16)acc[mt][0][r];
        p1[r] = (_Float16)acc[mt][1][r];
      }
      *(f16x4*)&StL[lm * STP + h] = p0;
      *(f16x4*)&StL[(16 + lm) * STP + h] = p1;
    }
    __syncthreads();
    // ---- output: O += Q . St (wave w owns rows s0 + w*16 .. +15) ----
    f32x4 o0a = {0.f,0.f,0.f,0.f}, o0b = {0.f,0.f,0.f,0.f};
    f32x4 o1a = {0.f,0.f,0.f,0.f}, o1b = {0.f,0.f,0.f,0.f};
    const size_t qrow = ((size_t)b * S_ + s0 + w * 16 + lm) * H_ + qd * 8;
#pragma unroll 3
    for (int kt = 0; kt < 24; kt += 2) {
      f16x8 qa = *(const f16x8*)&Qb[qrow + kt * 32];
      f16x8 qb2 = *(const f16x8*)&Qb[qrow + kt * 32 + 32];
      f16x8 s00 = *(f16x8*)&StL[lm * STP + kt * 32 + qd * 8];
      f16x8 s01 = *(f16x8*)&StL[(16 + lm) * STP + kt * 32 + qd * 8];
      f16x8 s10 = *(f16x8*)&StL[lm * STP + kt * 32 + 32 + qd * 8];
      f16x8 s11 = *(f16x8*)&StL[(16 + lm) * STP + kt * 32 + 32 + qd * 8];
      o0a = __builtin_amdgcn_mfma_f32_16x16x32_f16(qa, s00, o0a, 0, 0, 0);
      o1a = __builtin_amdgcn_mfma_f32_16x16x32_f16(qa, s01, o1a, 0, 0, 0);
      o0b = __builtin_amdgcn_mfma_f32_16x16x32_f16(qb2, s10, o0b, 0, 0, 0);
      o1b = __builtin_amdgcn_mfma_f32_16x16x32_f16(qb2, s11, o1b, 0, 0, 0);
    }
    const f32x4 o0 = o0a + o0b;
    const f32x4 o1 = o1a + o1b;
    const size_t orow = ((size_t)b * S_ + s0 + w * 16 + qd * 4) * H_ + d0;
#pragma unroll
    for (int r = 0; r < 4; ++r) {
      O[orow + (size_t)r * H_ + lm] += o0[r];
      O[orow + (size_t)r * H_ + 16 + lm] += o1[r];
    }
  }
}

// ---------------------------------------------------------------------------
extern "C" void kernel_launch(void* const* d_in, const int* in_sizes, int n_in,
                              void* d_out, int out_size, void* d_ws, size_t ws_size,
                              hipStream_t stream) {
  (void)in_sizes; (void)n_in; (void)out_size; (void)ws_size;
  const float* x    = (const float*)d_in[0];
  const float* Wq   = (const float*)d_in[1];
  const float* Wk   = (const float*)d_in[2];
  const float* Wv   = (const float*)d_in[3];
  const float* W1   = (const float*)d_in[4];
  const float* W2   = (const float*)d_in[5];
  const float* bias = (const float*)d_in[6];
  float* O = (float*)d_out;

  // workspace: Qb,Vb (row-major f16), KT,VT (transposed f16), weightsT, tbuf, abuf
  char* ws = (char*)d_ws;
  _Float16* Qb  = (_Float16*)ws;
  _Float16* Vb  = Qb + (size_t)M_ * H_;
  _Float16* KT  = Vb + (size_t)M_ * H_;
  _Float16* VT  = KT + (size_t)M_ * H_;
  _Float16* WqT = VT + (size_t)M_ * H_;
  _Float16* WkT = WqT + H_ * H_;
  _Float16* WvT = WkT + H_ * H_;
  float* tbuf = (float*)(WvT + H_ * H_);
  float* abuf = tbuf + (size_t)M_ * 16;

  k_transpose<<<dim3(24, 24), 256, 0, stream>>>(Wq, WqT);
  k_transpose<<<dim3(24, 24), 256, 0, stream>>>(Wk, WkT);
  k_transpose<<<dim3(24, 24), 256, 0, stream>>>(Wv, WvT);
  k_gemm_qkv<<<dim3(512, 6), 256, 0, stream>>>(x, WqT, WkT, WvT, Qb, Vb, KT, VT);
  k_tgemm<<<dim3(512), 256, 0, stream>>>(x, W1, tbuf);
  k_areduce<<<dim3(24, 8), 256, 0, stream>>>(tbuf, W2, bias, abuf);
  k_scores_y<<<dim3(64, 8), 256, 0, stream>>>(Qb, KT, Vb, O);
  k_scan<<<dim3(24, 8), 256, 0, stream>>>(Qb, KT, VT, abuf, O);
}